// Round 8
// baseline (32.822 us; speedup 1.0000x reference)
//
#include <hip/hip_runtime.h>
#include <math.h>

// SparseMixer MoE routing: T tokens x 128 experts, top-2.
// R8: software-pipelined grid-stride. 4 lanes/token, 4 tokens/group at
// stride G, double-buffered prefetch (named buffers, fully unrolled) so the
// next token's loads are ALWAYS in flight during compute — R5/R6/R7 all
// timed as additive VALU+HBM (bursty issue at wave start only).
// Also: theta-threshold mask test. Since v >= x for all tested elements:
//   masked <=> (v-x)/max(|x|,v) > 0.02 <=> x < theta,
//   theta = v>=0 ? 0.98*v : v/0.98   (case analysis incl. x<0, v=0->NaN->kept,
//   and side-2's x[i1]=v1>v2 element which is always kept; its exp(0)=1 term
//   is removed via t2_sum - 1). Rounding band vs ref's divide ~1e-7 relative,
//   same class as R6/R7's multiply-compare (both passed absmax 0.0).
// Output (floats): out[0..2T) = indices as float; out[2T..4T) = values.

#define NEXPERTS 128
#define CHUNKS 8        // 8 float4 per lane = 32 elems; 4 lanes = 128
#define INV098 1.0204082f   // 1/0.98 rounded to f32

__device__ __forceinline__ void load_row(float4* X, const float* logits,
                                         int token, int sub) {
    const float4* p = reinterpret_cast<const float4*>(logits + (size_t)token * NEXPERTS);
    #pragma unroll
    for (int c = 0; c < CHUNKS; ++c) X[c] = p[sub + c * 4];
}

__device__ __forceinline__ void process_token(const float4* X, int sub,
                                              int token, float* out, int T)
{
    // ---- local top-2, local code L = 16*c + j (global e = 4*sub + L);
    // ascending (c,j) == ascending e => first-occurrence tie-break.
    float m1 = -INFINITY, m2 = -INFINITY;
    int   l1 = 0x7fffff, l2 = 0x7fffff;
    #pragma unroll
    for (int c = 0; c < CHUNKS; ++c) {
        const float xs[4] = {X[c].x, X[c].y, X[c].z, X[c].w};
        #pragma unroll
        for (int j = 0; j < 4; ++j) {
            const float xv = xs[j];
            const int   L  = 16 * c + j;
            if (xv > m1)      { m2 = m1; l2 = l1; m1 = xv; l1 = L; }
            else if (xv > m2) { m2 = xv; l2 = L; }
        }
    }
    int i1 = 4 * sub + l1;
    int i2 = 4 * sub + l2;

    // ---- 4-lane joint top-2 butterfly (ties -> smaller index), as R7.
    #pragma unroll
    for (int off = 2; off > 0; off >>= 1) {
        float om1 = __shfl_xor(m1, off); int oi1 = __shfl_xor(i1, off);
        float om2 = __shfl_xor(m2, off); int oi2 = __shfl_xor(i2, off);
        float w1, ws, lt; int wi1, wis, lti;
        if (om1 > m1 || (om1 == m1 && oi1 < i1)) {
            w1 = om1; wi1 = oi1; ws = om2; wis = oi2; lt = m1;  lti = i1;
        } else {
            w1 = m1;  wi1 = i1;  ws = m2;  wis = i2;  lt = om1; lti = oi1;
        }
        if (lt > ws || (lt == ws && lti < wis)) { m2 = lt; i2 = lti; }
        else                                    { m2 = ws; i2 = wis; }
        m1 = w1; i1 = wi1;
    }
    const float v1 = m1, v2 = m2;

    // ---- theta thresholds: kept_s <=> x >= theta_s
    const float th1 = v1 * (v1 >= 0.f ? 0.98f : INV098);
    const float th2 = v2 * (v2 >= 0.f ? 0.98f : INV098);

    // ---- dual masked sums, one exp per element (8 VALU/elem)
    float s1 = 0.f, t2 = 0.f;
    #pragma unroll
    for (int c = 0; c < CHUNKS; ++c) {
        const float xs[4] = {X[c].x, X[c].y, X[c].z, X[c].w};
        #pragma unroll
        for (int j = 0; j < 4; ++j) {
            const float xv = xs[j];
            const float ev = __expf(xv - v1);   // exp(x - v1)
            if (xv >= th1) s1 += ev;
            if (xv >= th2) t2 += ev;            // includes i1's exp(0)=1
        }
    }
    // ---- 4-lane sum butterfly
    #pragma unroll
    for (int off = 2; off > 0; off >>= 1) {
        s1 += __shfl_xor(s1, off);
        t2 += __shfl_xor(t2, off);
    }

    if (sub == 0) {
        const float s2 = (t2 - 1.0f) * __expf(v1 - v2);  // remove i1, rescale
        out[(size_t)token * 2 + 0] = (float)i1;
        out[(size_t)token * 2 + 1] = (float)i2;
        float* vals = out + (size_t)2 * T;
        vals[(size_t)token * 2 + 0] = 1.0f / s1;
        vals[(size_t)token * 2 + 1] = 1.0f / s2;
    }
}

__global__ __launch_bounds__(256, 4) void sparsemixer_route_kernel(
    const float* __restrict__ logits,
    float* __restrict__ out,
    int T)
{
    const int tid = blockIdx.x * blockDim.x + threadIdx.x;
    const int grp = tid >> 2;                       // 4 lanes per token
    const int sub = threadIdx.x & 3;
    const int G   = (gridDim.x * blockDim.x) >> 2;  // total groups

    // 4 tokens per group at stride G, double-buffered prefetch.
    // Static buffer names (no runtime-indexed register arrays).
    float4 A[CHUNKS], B[CHUNKS];

    const int t0 = grp, t1 = grp + G, t2_ = grp + 2 * G, t3 = grp + 3 * G;

    if (t0 < T) load_row(A, logits, t0, sub);
    if (t1 < T) load_row(B, logits, t1, sub);       // in flight during t0 compute
    if (t0 < T) process_token(A, sub, t0, out, T);
    if (t2_ < T) load_row(A, logits, t2_, sub);     // in flight during t1 compute
    if (t1 < T) process_token(B, sub, t1, out, T);
    if (t3 < T) load_row(B, logits, t3, sub);       // in flight during t2 compute
    if (t2_ < T) process_token(A, sub, t2_, out, T);
    if (t3 < T) process_token(B, sub, t3, out, T);
}

extern "C" void kernel_launch(void* const* d_in, const int* in_sizes, int n_in,
                              void* d_out, int out_size, void* d_ws, size_t ws_size,
                              hipStream_t stream) {
    const float* logits = (const float*)d_in[0];
    float* out = (float*)d_out;
    const int T = in_sizes[0] / NEXPERTS;

    // 64 groups/block x 4 tokens/group = 256 tokens per block
    const int blocks = (T + 255) / 256;
    sparsemixer_route_kernel<<<blocks, 256, 0, stream>>>(logits, out, T);
}

// Round 10
// 27.023 us; speedup vs baseline: 1.2146x; 1.2146x over previous
//
#include <hip/hip_runtime.h>
#include <math.h>

// SparseMixer MoE routing: T tokens x 128 experts, top-2.
// R9 resubmission (round 9 died with UnresponsiveContainer before any run).
// Occupancy/desync round: R5-R8 all timed additive (VALU + HBM, ~32.5us
// plateau = 21.3us mem + ~9us VALU + overhead): at 4 waves/SIMD the
// identically-phased waves convoy — all compute while HBM idles, all wait
// while VALU idles. Fix: 8 waves/SIMD (VGPR <= 64) + block churn for desync.
//   - 8 lanes/token, ONE token per group, no prefetch: data = 4xfloat4 =
//     16 VGPR, total ~45-55 -> fits the 64-reg/8-wave budget.
//   - each chunk load = one full 128B line per 8-lane group (perfect lines).
// Semantics identical to R8 (passed, absmax 0.002):
//   top-2 first-occurrence tie-break == ref {argmax; -inf; argmax}
//   masked <=> x < theta, theta = v>=0 ? 0.98v : v*(1/0.98)  [v>=x always]
//   s1 = sum_{x>=th1} exp(x-v1); s2 = (sum_{x>=th2} exp(x-v1) - 1)*exp(v1-v2)
//   (x[i1]=v1 always passes th2; its exp(0)=1 term removed by the -1)
// Output (floats): out[0..2T) = indices as float; out[2T..4T) = values.

#define NEXPERTS 128
#define INV098 1.0204082f

__global__ __launch_bounds__(256, 8) void sparsemixer_route_kernel(
    const float* __restrict__ logits,
    float* __restrict__ out,
    int T)
{
    const int tid   = blockIdx.x * blockDim.x + threadIdx.x;
    const int token = tid >> 3;            // 8 lanes per token
    const int sub   = threadIdx.x & 7;
    if (token >= T) return;

    const float4* p = reinterpret_cast<const float4*>(logits + (size_t)token * NEXPERTS);
    float4 X[4];
    #pragma unroll
    for (int c = 0; c < 4; ++c) X[c] = p[sub + c * 8];   // one 128B line/group/instr

    // ---- local top-2 over this lane's 16 elements.
    // global e = 4*sub + L with L = 32*c + j; ascending (c,j) scan ==
    // ascending e => first-occurrence tie-break within lane.
    float m1 = -INFINITY, m2 = -INFINITY;
    int   l1 = 0x7fffff, l2 = 0x7fffff;
    #pragma unroll
    for (int c = 0; c < 4; ++c) {
        const float xs[4] = {X[c].x, X[c].y, X[c].z, X[c].w};
        #pragma unroll
        for (int j = 0; j < 4; ++j) {
            const float xv = xs[j];
            const int   L  = 32 * c + j;
            if (xv > m1)      { m2 = m1; l2 = l1; m1 = xv; l1 = L; }
            else if (xv > m2) { m2 = xv; l2 = L; }
        }
    }
    int i1 = 4 * sub + l1;   // global expert indices
    int i2 = 4 * sub + l2;

    // ---- 8-lane joint top-2 butterfly (offsets 4,2,1 stay in the group).
    // Merge keeps {winner.top, best(winner.second, loser.top)}; ties -> smaller idx.
    #pragma unroll
    for (int off = 4; off > 0; off >>= 1) {
        float om1 = __shfl_xor(m1, off); int oi1 = __shfl_xor(i1, off);
        float om2 = __shfl_xor(m2, off); int oi2 = __shfl_xor(i2, off);
        float w1, ws, lt; int wi1, wis, lti;
        if (om1 > m1 || (om1 == m1 && oi1 < i1)) {
            w1 = om1; wi1 = oi1; ws = om2; wis = oi2; lt = m1;  lti = i1;
        } else {
            w1 = m1;  wi1 = i1;  ws = m2;  wis = i2;  lt = om1; lti = oi1;
        }
        if (lt > ws || (lt == ws && lti < wis)) { m2 = lt; i2 = lti; }
        else                                    { m2 = ws; i2 = wis; }
        m1 = w1; i1 = wi1;
    }
    const float v1 = m1, v2 = m2;

    // ---- theta thresholds: kept_s <=> x >= theta_s
    const float th1 = v1 * (v1 >= 0.f ? 0.98f : INV098);
    const float th2 = v2 * (v2 >= 0.f ? 0.98f : INV098);

    // ---- dual masked sums, one exp per element
    float s1 = 0.f, t2 = 0.f;
    #pragma unroll
    for (int c = 0; c < 4; ++c) {
        const float xs[4] = {X[c].x, X[c].y, X[c].z, X[c].w};
        #pragma unroll
        for (int j = 0; j < 4; ++j) {
            const float xv = xs[j];
            const float ev = __expf(xv - v1);
            if (xv >= th1) s1 += ev;
            if (xv >= th2) t2 += ev;   // includes i1's exp(0)=1
        }
    }
    // ---- 8-lane sum butterfly
    #pragma unroll
    for (int off = 4; off > 0; off >>= 1) {
        s1 += __shfl_xor(s1, off);
        t2 += __shfl_xor(t2, off);
    }

    if (sub == 0) {
        const float s2 = (t2 - 1.0f) * __expf(v1 - v2);  // remove i1, rescale
        out[(size_t)token * 2 + 0] = (float)i1;
        out[(size_t)token * 2 + 1] = (float)i2;
        float* vals = out + (size_t)2 * T;
        vals[(size_t)token * 2 + 0] = 1.0f / s1;
        vals[(size_t)token * 2 + 1] = 1.0f / s2;
    }
}

extern "C" void kernel_launch(void* const* d_in, const int* in_sizes, int n_in,
                              void* d_out, int out_size, void* d_ws, size_t ws_size,
                              hipStream_t stream) {
    const float* logits = (const float*)d_in[0];
    float* out = (float*)d_out;
    const int T = in_sizes[0] / NEXPERTS;

    // 32 tokens per 256-thread block (8 lanes each)
    const int blocks = (T + 31) / 32;
    sparsemixer_route_kernel<<<blocks, 256, 0, stream>>>(logits, out, T);
}